// Round 3
// baseline (141.601 us; speedup 1.0000x reference)
//
#include <hip/hip_runtime.h>
#include <hip/hip_bf16.h>
#include <stdint.h>

#define N_RES 256
#define CMDIM 256

typedef __attribute__((ext_vector_type(8))) short bf16x8;
typedef __attribute__((ext_vector_type(4))) float f32x4;
typedef __attribute__((ext_vector_type(2))) unsigned int u32x2;

__device__ __forceinline__ unsigned short f32_to_bf16(float f) {
    union { float f; unsigned int u; } v; v.f = f;
    unsigned int u = v.u;
    return (unsigned short)((u + 0x7FFFu + ((u >> 16) & 1u)) >> 16);
}

// Bank-spreading chunk swizzle for 32-pair o tiles (phys in [0,32)):
// chunk bits 2-4 (write-side lane variation = column l15 low bits) -> phys 0-2
// (the bank field), chunk bit 5 -> phys 3, chunk bit 0 -> phys 4.
__device__ __forceinline__ int swz5(int x) {
    return ((x >> 2) & 7) | (((x >> 5) & 1) << 3) | ((x & 1) << 4);
}

// Fragment-linear layouts (all bf16):
//   A2f/B2f: element(row, s)  -> ((row>>4)*4  + (s>>5))*512 + ((s>>3)&3)*128 + (row&15)*8 + (s&7)
//   Wbf:     element(ch, cm)  -> ((ch>>4)*8  + (cm>>5))*512 + ((cm>>3)&3)*128 + (ch&15)*8 + (cm&7)
//   wof:     element(zo, k)   -> ((zo>>4)*32 + (k>>5))*512 + ((k>>3)&3)*128 + (zo&15)*8 + (k&7)
// A wave reading (blk, ks) does one coalesced 1 KB load at base + lane*16B.

// ---------------- K0: convert + repack weights ----------------
__global__ __launch_bounds__(256) void k_prep(
    const float* __restrict__ w1, const float* __restrict__ w2,
    const float* __restrict__ wo,
    unsigned short* __restrict__ Wbf, unsigned short* __restrict__ wof)
{
    int t = blockIdx.x * 256 + threadIdx.x;
    if (t < 16384) {
        int ch = t >> 8, cm = t & 255;
        float v = (ch < 32) ? w1[ch * 256 + cm] : w2[(ch - 32) * 256 + cm];
        int addr = ((ch >> 4) * 8 + (cm >> 5)) * 512 + ((cm >> 3) & 3) * 128 + (ch & 15) * 8 + (cm & 7);
        Wbf[addr] = f32_to_bf16(v);
    }
    if (t < 131072) {
        int zo = t >> 10, k = t & 1023;
        int addr = ((zo >> 4) * 32 + (k >> 5)) * 512 + ((k >> 3) & 3) * 128 + (zo & 15) * 8 + (k & 7);
        wof[addr] = f32_to_bf16(wo[t]);
    }
}

// ---------------- K1: LayerNorm + dual projection ----------------
__global__ __launch_bounds__(256) void k_ln_proj(
    const float* __restrict__ m, const float* __restrict__ lnw, const float* __restrict__ lnb,
    const float* __restrict__ b1, const float* __restrict__ b2,
    const unsigned short* __restrict__ Wbf,
    unsigned short* __restrict__ A2f, unsigned short* __restrict__ B2f)
{
    __shared__ unsigned short mn[32 * 256];   // 16 KB
    __shared__ unsigned short stg[2048];      // 4 KB epilogue staging
    int b = blockIdx.x;
    int i = b >> 2, sblk = b & 3;
    int tid = threadIdx.x;
    int wv = tid >> 6, lane = tid & 63;
    int quad = lane >> 4, l15 = lane & 15;

    f32x4 lw = *(const f32x4*)(lnw + lane * 4);
    f32x4 lb = *(const f32x4*)(lnb + lane * 4);

    #pragma unroll
    for (int r = 0; r < 8; ++r) {
        int sl = wv * 8 + r;
        int s = sblk * 32 + sl;
        const float* row = m + ((size_t)s * N_RES + i) * CMDIM;
        f32x4 x = *(const f32x4*)(row + lane * 4);
        float s1 = x[0] + x[1] + x[2] + x[3];
        float s2 = x[0]*x[0] + x[1]*x[1] + x[2]*x[2] + x[3]*x[3];
        #pragma unroll
        for (int off = 32; off; off >>= 1) {
            s1 += __shfl_xor(s1, off);
            s2 += __shfl_xor(s2, off);
        }
        float mu = s1 * (1.0f / 256.0f);
        float var = s2 * (1.0f / 256.0f) - mu * mu;
        float rstd = rsqrtf(var + 1e-5f);
        float n0 = (x[0] - mu) * rstd * lw[0] + lb[0];
        float n1 = (x[1] - mu) * rstd * lw[1] + lb[1];
        float n2 = (x[2] - mu) * rstd * lw[2] + lb[2];
        float n3 = (x[3] - mu) * rstd * lw[3] + lb[3];
        unsigned int p0 = (unsigned)f32_to_bf16(n0) | ((unsigned)f32_to_bf16(n1) << 16);
        unsigned int p1 = (unsigned)f32_to_bf16(n2) | ((unsigned)f32_to_bf16(n3) << 16);
        int chunk = lane >> 1;
        int pos = (chunk & 16) | ((chunk ^ sl) & 15);
        unsigned int* dst = (unsigned int*)((char*)mn + sl * 512 + pos * 16 + (lane & 1) * 8);
        dst[0] = p0; dst[1] = p1;
    }
    __syncthreads();

    bf16x8 af[8];
    #pragma unroll
    for (int ks = 0; ks < 8; ++ks)
        af[ks] = *(const bf16x8*)(Wbf + (wv * 8 + ks) * 512 + lane * 8);

    f32x4 acc[2];
    acc[0] = (f32x4){0.f, 0.f, 0.f, 0.f};
    acc[1] = (f32x4){0.f, 0.f, 0.f, 0.f};
    #pragma unroll
    for (int ks = 0; ks < 8; ++ks) {
        #pragma unroll
        for (int nb = 0; nb < 2; ++nb) {
            int sl = nb * 16 + l15;
            int chunk = ks * 4 + quad;
            int pos = (chunk & 16) | ((chunk ^ sl) & 15);
            bf16x8 bf = *(const bf16x8*)((char*)mn + sl * 512 + pos * 16);
            acc[nb] = __builtin_amdgcn_mfma_f32_16x16x32_bf16(af[ks], bf, acc[nb], 0, 0, 0);
        }
    }

    const float* bsrc = (wv < 2) ? b1 : b2;
    f32x4 bias = *(const f32x4*)(bsrc + (wv & 1) * 16 + quad * 4);
    unsigned short* sbase = stg + (wv >> 1) * 1024 + (wv & 1) * 512 + quad * 32;
    #pragma unroll
    for (int nb = 0; nb < 2; ++nb) {
        int sl = nb * 16 + l15;
        int soff = ((sl >> 3) & 3) * 128 + (sl & 7);
        #pragma unroll
        for (int reg = 0; reg < 4; ++reg)
            sbase[soff + reg * 8] = f32_to_bf16(acc[nb][reg] + bias[reg]);
    }
    __syncthreads();

    int part = tid >> 7, blk = (tid >> 6) & 1, l = tid & 63;
    unsigned short* gdst = (part ? B2f : A2f) + ((i * 2 + blk) * 4 + sblk) * 512 + l * 8;
    *(bf16x8*)gdst = *(const bf16x8*)(stg + tid * 8);
}

// ---------------- K2: fused GEMM1+GEMM2, 32-pair tiles, v3 ----------------
// 2048 blocks (XCD-chunked), 256 threads = 4 waves, 64 KB LDS -> 2 blocks/CU.
// o LDS layout: byte = chunk*512 + (pair ^ swz5(chunk))*16 + (e&7)*2,
//   chunk = e>>3 in [0,128), e = c*32+d, pair = il*8+jl in [0,32).
// Stage A: 2 passes over j-halves, acc[4][4], full per-pass am[4][4] preload.
// Stage B: wave zg in [0,4) covers 32 zo x all 32 pairs, full K; 2-kt ring
//   steps (8 MFMA each), ring-4 => 6-kt global prefetch distance.
__global__ __launch_bounds__(256, 2) void k_fused(
    const unsigned short* __restrict__ A2f, const unsigned short* __restrict__ B2f,
    const unsigned short* __restrict__ wof, const float* __restrict__ bo,
    float* __restrict__ out)
{
    __shared__ char olds[65536];
    int bid = blockIdx.x;
    int sb = (bid & 7) * 256 + (bid >> 3);   // bijective XCD chunking (2048%8==0)
    int bx = sb & 63, by = sb >> 6;          // bx: 4 i's, by: 8 j's
    int tid = threadIdx.x, wv = tid >> 6, lane = tid & 63;
    int quad = lane >> 4, l15 = lane & 15;
    int wm = wv & 1, wn = wv >> 1;           // wm: j-row half, wn: col half

    // ---- Stage A: o[32 pairs][1024] = (8j x 32d) x (4i x 32c), K = 128 s ----
    const unsigned short* Abase = A2f + (size_t)((bx * 8 + wn * 4) * 4) * 512 + lane * 8;

    bf16x8 bn[4][4];                          // held A-side (cols) frags
    #pragma unroll
    for (int nb = 0; nb < 4; ++nb)
        #pragma unroll
        for (int ks = 0; ks < 4; ++ks)
            bn[ks][nb] = *(const bf16x8*)(Abase + (size_t)(nb * 4 + ks) * 512);

    #pragma unroll
    for (int pass = 0; pass < 2; ++pass) {
        const unsigned short* Bbase = B2f + (size_t)((by * 16 + pass * 8 + wm * 4) * 4) * 512 + lane * 8;
        f32x4 acc[4][4];
        #pragma unroll
        for (int a = 0; a < 4; ++a)
            #pragma unroll
            for (int b = 0; b < 4; ++b) acc[a][b] = (f32x4){0.f, 0.f, 0.f, 0.f};

        // full per-pass B-side preload: one latency bubble per pass
        bf16x8 am[4][4];
        #pragma unroll
        for (int mb = 0; mb < 4; ++mb)
            #pragma unroll
            for (int ks = 0; ks < 4; ++ks)
                am[ks][mb] = *(const bf16x8*)(Bbase + (size_t)(mb * 4 + ks) * 512);

        __builtin_amdgcn_s_setprio(1);
        #pragma unroll
        for (int ks = 0; ks < 4; ++ks)
            #pragma unroll
            for (int mb = 0; mb < 4; ++mb)
                #pragma unroll
                for (int nb = 0; nb < 4; ++nb)
                    acc[mb][nb] = __builtin_amdgcn_mfma_f32_16x16x32_bf16(am[ks][mb], bn[ks][nb], acc[mb][nb], 0, 0, 0);
        __builtin_amdgcn_s_setprio(0);

        // o-write: row m_=(jl,d) (B2f side), col n_=(il,c) (A2f side)
        #pragma unroll
        for (int mb = 0; mb < 4; ++mb) {
            int m_ = wm * 64 + mb * 16 + quad * 4;
            int d0 = m_ & 31;
            int jl = pass * 4 + (m_ >> 5);
            #pragma unroll
            for (int nb = 0; nb < 4; ++nb) {
                int n_ = wn * 64 + nb * 16 + l15;
                int c = n_ & 31, il = n_ >> 5;
                int pair = il * 8 + jl;
                int e0 = c * 32 + d0;
                int chunk = e0 >> 3;
                int phys = pair ^ swz5(chunk);
                f32x4 a4 = acc[mb][nb];
                unsigned int p0 = (unsigned)f32_to_bf16(a4[0]) | ((unsigned)f32_to_bf16(a4[1]) << 16);
                unsigned int p1 = (unsigned)f32_to_bf16(a4[2]) | ((unsigned)f32_to_bf16(a4[3]) << 16);
                u32x2 pv = {p0, p1};
                *(u32x2*)(olds + chunk * 512 + phys * 16 + (e0 & 7) * 2) = pv;
            }
        }
    }

    // ---- Stage B: wave zg covers D[32 zo][32 pair], full K=1024 ----
    // 2-kt steps: 8 MFMA/step; ring-4 slots => prefetch distance 6 kt.
    int zg = wv;
    const unsigned short* wbase = wof + (size_t)(zg * 64) * 512 + lane * 8;

    bf16x8 af2[4][4], bfr2[4][4];
    // wof prologue (steps 0..2) BEFORE the barrier: no LDS dependency,
    // latency overlaps the o-write epilogue + barrier drain.
    #pragma unroll
    for (int p = 0; p < 3; ++p)
        #pragma unroll
        for (int zb = 0; zb < 2; ++zb)
            #pragma unroll
            for (int h = 0; h < 2; ++h)
                af2[p][zb * 2 + h] = *(const bf16x8*)(wbase + (size_t)(zb * 32 + 2 * p + h) * 512);

    __syncthreads();

    #pragma unroll
    for (int p = 0; p < 3; ++p)
        #pragma unroll
        for (int pb = 0; pb < 2; ++pb)
            #pragma unroll
            for (int h = 0; h < 2; ++h) {
                int kt = 2 * p + h;
                int pair = pb * 16 + l15;
                int chunk = kt * 4 + quad;
                int phys = pair ^ swz5(chunk);
                bfr2[p][pb * 2 + h] = *(const bf16x8*)(olds + chunk * 512 + phys * 16);
            }

    f32x4 acc2[2][2];
    #pragma unroll
    for (int a = 0; a < 2; ++a)
        #pragma unroll
        for (int b = 0; b < 2; ++b) acc2[a][b] = (f32x4){0.f, 0.f, 0.f, 0.f};

    #pragma unroll
    for (int s = 0; s < 16; ++s) {
        int slot = s & 3;
        if (s < 13) {
            int t = s + 3, ps = t & 3;
            #pragma unroll
            for (int zb = 0; zb < 2; ++zb)
                #pragma unroll
                for (int h = 0; h < 2; ++h)
                    af2[ps][zb * 2 + h] = *(const bf16x8*)(wbase + (size_t)(zb * 32 + 2 * t + h) * 512);
            #pragma unroll
            for (int pb = 0; pb < 2; ++pb)
                #pragma unroll
                for (int h = 0; h < 2; ++h) {
                    int kt = 2 * t + h;
                    int pair = pb * 16 + l15;
                    int chunk = kt * 4 + quad;
                    int phys = pair ^ swz5(chunk);
                    bfr2[ps][pb * 2 + h] = *(const bf16x8*)(olds + chunk * 512 + phys * 16);
                }
        }
        __builtin_amdgcn_s_setprio(1);
        #pragma unroll
        for (int h = 0; h < 2; ++h)
            #pragma unroll
            for (int zb = 0; zb < 2; ++zb)
                #pragma unroll
                for (int pb = 0; pb < 2; ++pb)
                    acc2[zb][pb] = __builtin_amdgcn_mfma_f32_16x16x32_bf16(
                        af2[slot][zb * 2 + h], bfr2[slot][pb * 2 + h], acc2[zb][pb], 0, 0, 0);
        __builtin_amdgcn_s_setprio(0);
    }

    // epilogue: z = (acc + bo) / n_seq
    #pragma unroll
    for (int zb = 0; zb < 2; ++zb) {
        int zo = zg * 32 + zb * 16 + quad * 4;
        f32x4 b4 = *(const f32x4*)(bo + zo);
        #pragma unroll
        for (int pb = 0; pb < 2; ++pb) {
            int pair = pb * 16 + l15;
            int i = bx * 4 + (pair >> 3);
            int j = by * 8 + (pair & 7);
            f32x4 v;
            #pragma unroll
            for (int reg = 0; reg < 4; ++reg)
                v[reg] = (acc2[zb][pb][reg] + b4[reg]) * (1.0f / 128.0f);
            *(f32x4*)(out + ((size_t)(i * 256 + j)) * 128 + zo) = v;
        }
    }
}

extern "C" void kernel_launch(void* const* d_in, const int* in_sizes, int n_in,
                              void* d_out, int out_size, void* d_ws, size_t ws_size,
                              hipStream_t stream) {
    const float* m   = (const float*)d_in[0];
    const float* lnw = (const float*)d_in[1];
    const float* lnb = (const float*)d_in[2];
    const float* w1  = (const float*)d_in[3];
    const float* b1  = (const float*)d_in[4];
    const float* w2  = (const float*)d_in[5];
    const float* b2  = (const float*)d_in[6];
    const float* wo  = (const float*)d_in[7];
    const float* bo  = (const float*)d_in[8];
    float* out = (float*)d_out;
    char* ws = (char*)d_ws;

    unsigned short* Wbf = (unsigned short*)(ws);                            // 32 KB
    unsigned short* wof = (unsigned short*)(ws + 32768);                    // 256 KB
    unsigned short* A2f = (unsigned short*)(ws + 32768 + 262144);           // 2 MB
    unsigned short* B2f = (unsigned short*)(ws + 32768 + 262144 + 2097152); // 2 MB

    hipLaunchKernelGGL(k_prep, dim3(512), dim3(256), 0, stream, w1, w2, wo, Wbf, wof);
    hipLaunchKernelGGL(k_ln_proj, dim3(1024), dim3(256), 0, stream,
                       m, lnw, lnb, b1, b2, Wbf, A2f, B2f);
    hipLaunchKernelGGL(k_fused, dim3(2048), dim3(256), 0, stream,
                       A2f, B2f, wof, bo, out);
}